// Round 1
// 190.254 us; speedup vs baseline: 1.0566x; 1.0566x over previous
//
#include <hip/hip_runtime.h>
#include <hip/hip_bf16.h>
#include <math.h>

// Problem constants
#define BATCH 2
#define SLEN  2048
#define DIN   1024
#define DMODEL 1024
#define NHEAD 16
#define HD    64
#define E3    3072   // 3*DMODEL, row width of qkv

typedef unsigned short us;
typedef _Float16 f16;
typedef __attribute__((ext_vector_type(8))) _Float16 f16x8;
typedef __attribute__((ext_vector_type(2))) _Float16 f16x2;
typedef __attribute__((ext_vector_type(8))) unsigned short us8;
typedef __attribute__((ext_vector_type(4))) unsigned short us4;
typedef __attribute__((ext_vector_type(4))) float f32x4;
typedef __attribute__((ext_vector_type(16))) float f32x16;
typedef __attribute__((ext_vector_type(4))) unsigned int u32x4;

// 0.125 (1/sqrt(HD)) * log2(e): folded into Q at qkv-GEMM epilogue so the
// attention softmax is a bare exp2 of the raw MFMA score.
#define QSCALE 0.18033688011112042f

__device__ __forceinline__ us f16bits(float x) {
    const f16 h = (f16)x;
    return __builtin_bit_cast(us, h);
}

// pack two f32 -> one dword of two f16 (RTZ)
__device__ __forceinline__ unsigned int pkrtz(float a, float b) {
    return __builtin_bit_cast(unsigned int, __builtin_amdgcn_cvt_pkrtz(a, b));
}

// v_permlane32_swap_b32: a' = {a.lo, b.lo}, b' = {a.hi, b.hi}
// (swaps upper 32 lanes of dst with lower 32 lanes of src)
__device__ __forceinline__ void plswap(unsigned int& a, unsigned int& b) {
    asm volatile("v_permlane32_swap_b32 %0, %1" : "+v"(a), "+v"(b));
}

// async 16B global->LDS (lane i deposits at ldsbase + i*16)
#define GLL16(g, l)                                                                     \
    __builtin_amdgcn_global_load_lds((const __attribute__((address_space(1))) unsigned int*)(g), \
                                     (__attribute__((address_space(3))) unsigned int*)(l), 16, 0, 0)

// ---------------- fp32 -> fp16 for x, w_qkv, w_o in one launch ----------------
__global__ __launch_bounds__(256) void cvt3_f16(
    const float* __restrict__ x, us* __restrict__ ox, int nx,
    const float* __restrict__ wq, us* __restrict__ owq, int nq,
    const float* __restrict__ wo, us* __restrict__ owo)
{
    int i = (blockIdx.x * 256 + threadIdx.x) * 8;
    const float* s;
    us* o;
    if (i < nx)           { s = x;  o = ox; }
    else if (i < nx + nq) { s = wq; o = owq; i -= nx; }
    else                  { s = wo; o = owo; i -= nx + nq; }
    const float4 f0 = *(const float4*)&s[i];
    const float4 f1 = *(const float4*)&s[i + 4];
    const float v[8] = {f0.x, f0.y, f0.z, f0.w, f1.x, f1.y, f1.z, f1.w};
    us8 h;
#pragma unroll
    for (int j = 0; j < 8; ++j) h[j] = f16bits(v[j]);
    *(us8*)&o[i] = h;
}

// ---------------- single-fp16 MFMA GEMM ----------------
// C[M,N] = A[M,K] * B[N,K]^T + bias[N], all fp16 inputs, fp32 accumulate.
// 128x128 tile, BK=32, 256 thr = 4 waves (2x2), 4x4 16x16 tiles per wave.
// QKV_OUT: write fp16 and pre-scale Q columns (col%192 < 64) by QSCALE.
template <bool QKV_OUT>
__global__ __launch_bounds__(256) void gemm_f16(
    const us* __restrict__ Am, const us* __restrict__ Bm,
    const float* __restrict__ bias, void* __restrict__ Cout,
    int M, int N, int K)
{
    __shared__ __align__(16) us As[128 * 32];
    __shared__ __align__(16) us Bs[128 * 32];

    const int t    = threadIdx.x;
    const int lane = t & 63;
    const int w    = t >> 6;
    const int ml   = lane & 15;
    const int quad = lane >> 4;
    const int wm   = w >> 1;
    const int wn   = w & 1;

    const int m0 = blockIdx.y * 128;
    const int n0 = blockIdx.x * 128;

    const int srow = (lane >> 2);
    const int scol = (lane & 3) * 8;

    const us* pA = Am + (size_t)(m0 + w * 32 + srow) * K + scol;
    const us* pB = Bm + (size_t)(n0 + w * 32 + srow) * K + scol;
    const size_t rstep = (size_t)16 * K;

    us* lA0 = &As[(w * 32) * 32];
    us* lA1 = &As[(w * 32 + 16) * 32];
    us* lB0 = &Bs[(w * 32) * 32];
    us* lB1 = &Bs[(w * 32 + 16) * 32];

    f32x4 acc[4][4];
#pragma unroll
    for (int i = 0; i < 4; ++i)
#pragma unroll
        for (int j = 0; j < 4; ++j) {
            acc[i][j][0] = 0.f; acc[i][j][1] = 0.f; acc[i][j][2] = 0.f; acc[i][j][3] = 0.f;
        }

    for (int k0 = 0; k0 < K; k0 += 32) {
        __syncthreads();
        GLL16(pA + k0, lA0); GLL16(pA + k0 + rstep, lA1);
        GLL16(pB + k0, lB0); GLL16(pB + k0 + rstep, lB1);
        __syncthreads();

        f16x8 a[4];
#pragma unroll
        for (int i = 0; i < 4; ++i)
            a[i] = __builtin_bit_cast(f16x8, *(const us8*)&As[(wm * 64 + i * 16 + ml) * 32 + quad * 8]);
#pragma unroll
        for (int j = 0; j < 4; ++j) {
            const f16x8 b = __builtin_bit_cast(f16x8, *(const us8*)&Bs[(wn * 64 + j * 16 + ml) * 32 + quad * 8]);
#pragma unroll
            for (int i = 0; i < 4; ++i)
                acc[i][j] = __builtin_amdgcn_mfma_f32_16x16x32_f16(a[i], b, acc[i][j], 0, 0, 0);
        }
    }

    float bj[4], cs[4];
#pragma unroll
    for (int j = 0; j < 4; ++j) {
        const int col = n0 + wn * 64 + j * 16 + ml;
        bj[j] = bias[col];
        cs[j] = (QKV_OUT && (col % 192) < 64) ? QSCALE : 1.0f;
    }

#pragma unroll
    for (int i = 0; i < 4; ++i) {
#pragma unroll
        for (int r = 0; r < 4; ++r) {
            const size_t rowoff = (size_t)(m0 + wm * 64 + i * 16 + quad * 4 + r) * N;
#pragma unroll
            for (int j = 0; j < 4; ++j) {
                const int col = n0 + wn * 64 + j * 16 + ml;
                const float v = (acc[i][j][r] + bj[j]) * cs[j];
                if (QKV_OUT) ((us*)Cout)[rowoff + col] = f16bits(v);
                else         ((float*)Cout)[rowoff + col] = v;
            }
        }
    }
}

// ---------------- MFMA flash attention, 32x32 shape, transposed-score ----------------
// 512 thr = 8 waves. In-block KEY SPLIT: waves 0-3 (sp=0) do chunks [0,16),
// waves 4-7 (sp=1) do chunks [16,32), over the SAME 128 Q rows (staged once).
// Per split: 4 waves x 32 q; 64-key chunks; Q pre-scaled so p = exp2(score).
// S^T = K.Q^T via mfma_f32_32x32x16_f16. P never touches LDS: T12 in-register
// redistribution (v_cvt_pkrtz pairs + v_permlane32_swap) builds the PV B-frags
// directly from the QK^T C-layout. O^T += V^T.P^T.
// Epilogue: split-1 writes raw f32 O + l into the dead K/V LDS area; split-0
// adds, normalizes by (l0+l1), stores fp16 (exact: no running max -> sums add).
// Fragment maps (32x32x16): A[m=lane&31][k=(lane>>5)*8+j]; B[k][n=lane&31];
// C/D: col=lane&31, row=(reg&3)+8*(reg>>2)+4*(lane>>5)  [m74/m101-verified].
#define ABQ 128
#define ACH 64
#define NCH (SLEN / ACH)    // 32
#define NCH2 (NCH / 2)      // 16 chunks per split
#define LQA 72              // LDS row stride in fp16 elems (36 words)
#define OSTR 68             // combine-scratch row stride in f32 (16B-aligned, 4-way banks)

__global__ __launch_bounds__(512, 4) void attn_mfma(
    const us* __restrict__ qkvh, us* __restrict__ vals)
{
    // Q: 128x72 | K: 2 splits x 64x72 | V^T: 2 splits x 64x72  (55296 B)
    __shared__ __align__(16) us smem[27648];
    us* const Qs = smem;            // 9216 us
    us* const Ks = smem + 9216;     // 9216 us (2 x 4608)
    us* const Vt = smem + 18432;    // 9216 us (2 x 4608)

    const int t    = threadIdx.x;
    const int lane = t & 63;
    const int w    = t >> 6;        // wave 0..7
    const int sp   = w >> 2;        // key split 0/1
    const int wq4  = w & 3;         // q-group within split
    const int t2   = t & 255;       // thread id within split
    const int m32  = lane & 31;
    const int half = lane >> 5;

    const int bh = blockIdx.y;
    const int b  = bh >> 4;
    const int h  = bh & 15;
    const int q0 = blockIdx.x * ABQ;

    const size_t base = (size_t)b * SLEN * E3;
    const int qoff = h * 192;

    // ---- stage Q (128 q x 64 d): 16 elems / thread ----
    {
        const int row = t >> 2;
        const int c0q = (t & 3) * 16;
        const us* g = &qkvh[base + (size_t)(q0 + row) * E3 + qoff + c0q];
        *(us8*)&Qs[row * LQA + c0q]     = *(const us8*)g;
        *(us8*)&Qs[row * LQA + c0q + 8] = *(const us8*)(g + 8);
    }
    __syncthreads();

    // Q B-frags: B[k=dim][n=q], q = wq4*32 + m32 (same rows for both splits)
    f16x8 aq[4];
#pragma unroll
    for (int s = 0; s < 4; ++s)
        aq[s] = __builtin_bit_cast(f16x8, *(const us8*)&Qs[(wq4 * 32 + m32) * LQA + half * 8 + 16 * s]);

    // staging maps (within split)
    const int krA = t2 >> 2;          // K: key 0..63, 16 dims/thread
    const int ksA = (t2 & 3) * 16;
    const int k2  = t2 & 31;          // V: key PAIR (2*k2, 2*k2+1)
    const int d0v = (t2 >> 5) * 8;    // V: 8 dims/thread

    us* const myK = Ks + sp * 4608;
    us* const myV = Vt + sp * 4608;
    const int cg0 = sp * NCH2;        // this split's first chunk

    // prefetch first chunk into regs
    us8 kk0, kk1, vv0, vv1;
    {
        const us* gK = &qkvh[base + (size_t)(cg0 * ACH + krA) * E3 + qoff + 64 + ksA];
        kk0 = *(const us8*)gK; kk1 = *(const us8*)(gK + 8);
        const us* gV = &qkvh[base + (size_t)(cg0 * ACH + 2 * k2) * E3 + qoff + 128 + d0v];
        vv0 = *(const us8*)gV; vv1 = *(const us8*)(gV + E3);
    }

    f32x16 O[2];
#pragma unroll
    for (int dt = 0; dt < 2; ++dt)
#pragma unroll
        for (int r = 0; r < 16; ++r) O[dt][r] = 0.f;
    float lpart = 0.f;

    for (int c = 0; c < NCH2; ++c) {
        __syncthreads();   // previous chunk's Ks/Vt fully consumed (all 8 waves)
        // ---- regs -> LDS ----
        *(us8*)&myK[krA * LQA + ksA]     = kk0;
        *(us8*)&myK[krA * LQA + ksA + 8] = kk1;
#pragma unroll
        for (int j = 0; j < 8; ++j) {
            const unsigned int pv = (unsigned int)vv0[j] | ((unsigned int)vv1[j] << 16);
            *(unsigned int*)&myV[(d0v + j) * LQA + 2 * k2] = pv;
        }
        __syncthreads();
        // ---- prefetch next chunk (latency hidden behind compute) ----
        if (c + 1 < NCH2) {
            const int cg = cg0 + c + 1;
            const us* gK = &qkvh[base + (size_t)(cg * ACH + krA) * E3 + qoff + 64 + ksA];
            kk0 = *(const us8*)gK; kk1 = *(const us8*)(gK + 8);
            const us* gV = &qkvh[base + (size_t)(cg * ACH + 2 * k2) * E3 + qoff + 128 + d0v];
            vv0 = *(const us8*)gV; vv1 = *(const us8*)(gV + E3);
        }

        // ---- S^T = K.Q^T per key-tile; exp2; T12 in-register P redistribution ----
        f16x8 pf[4];
#pragma unroll
        for (int kt = 0; kt < 2; ++kt) {
            f32x16 z;
#pragma unroll
            for (int r = 0; r < 16; ++r) z[r] = 0.f;
#pragma unroll
            for (int s = 0; s < 4; ++s) {
                const f16x8 ak = __builtin_bit_cast(f16x8, *(const us8*)&myK[(kt * 32 + m32) * LQA + half * 8 + 16 * s]);
                z = __builtin_amdgcn_mfma_f32_32x32x16_f16(ak, aq[s], z, 0, 0, 0);
            }
            // reg r: key = kt*32 + (r&3) + 8*(r>>2) + 4*half, q = m32
            float p[16];
#pragma unroll
            for (int r = 0; r < 16; ++r) {
                p[r] = __builtin_amdgcn_exp2f(z[r]);
                lpart += p[r];
            }
            // groups g hold keys {8g + 4*half + 0..3}. Build B-frag words:
            // word for keys (8*half + 2i, +1) of each 16-key slab via one swap.
            unsigned int a0 = pkrtz(p[0],  p[1]),  a1 = pkrtz(p[2],  p[3]);
            unsigned int b0 = pkrtz(p[4],  p[5]),  b1 = pkrtz(p[6],  p[7]);
            plswap(a0, b0); plswap(a1, b1);
            pf[2 * kt] = __builtin_bit_cast(f16x8, (u32x4){a0, a1, b0, b1});
            unsigned int e0 = pkrtz(p[8],  p[9]),  e1 = pkrtz(p[10], p[11]);
            unsigned int f0 = pkrtz(p[12], p[13]), f1 = pkrtz(p[14], p[15]);
            plswap(e0, f0); plswap(e1, f1);
            pf[2 * kt + 1] = __builtin_bit_cast(f16x8, (u32x4){e0, e1, f0, f1});
        }

        // ---- O^T += V^T.P^T ----
#pragma unroll
        for (int dt = 0; dt < 2; ++dt) {
#pragma unroll
            for (int s = 0; s < 4; ++s) {
                const f16x8 av = __builtin_bit_cast(f16x8, *(const us8*)&myV[(dt * 32 + m32) * LQA + half * 8 + 16 * s]);
                O[dt] = __builtin_amdgcn_mfma_f32_32x32x16_f16(av, pf[s], O[dt], 0, 0, 0);
            }
        }
    }

    // ---- epilogue: combine the two key-splits through LDS, normalize, store ----
    const float l = lpart + __shfl_xor(lpart, 32);   // this split's denominator
    const int ql = wq4 * 32 + m32;                   // local q row 0..127

    __syncthreads();   // K/V LDS dead from here; reuse as f32 combine scratch
    float* const Osc = (float*)(smem + 9216);        // 128 x OSTR f32 (34816 B)
    float* const lsc = Osc + ABQ * OSTR;             // 128 f32

    if (sp == 1) {
#pragma unroll
        for (int dt = 0; dt < 2; ++dt) {
#pragma unroll
            for (int g = 0; g < 4; ++g) {
                const f32x4 o4 = {O[dt][g * 4], O[dt][g * 4 + 1], O[dt][g * 4 + 2], O[dt][g * 4 + 3]};
                *(f32x4*)&Osc[ql * OSTR + dt * 32 + 8 * g + 4 * half] = o4;
            }
        }
        if (half == 0) lsc[ql] = l;
    }
    __syncthreads();
    if (sp == 0) {
        const float rl = 1.0f / (l + lsc[ql]);
        const int sq = q0 + ql;
        const size_t rowbase = (size_t)(b * SLEN + sq) * DMODEL + h * HD;
#pragma unroll
        for (int dt = 0; dt < 2; ++dt) {
#pragma unroll
            for (int g = 0; g < 4; ++g) {
                const f32x4 part = *(const f32x4*)&Osc[ql * OSTR + dt * 32 + 8 * g + 4 * half];
                us4 o4;
#pragma unroll
                for (int r2 = 0; r2 < 4; ++r2)
                    o4[r2] = f16bits((O[dt][g * 4 + r2] + part[r2]) * rl);
                *(us4*)&vals[rowbase + dt * 32 + 8 * g + 4 * half] = o4;
            }
        }
    }
}

// ---------------- launch ----------------
extern "C" void kernel_launch(void* const* d_in, const int* in_sizes, int n_in,
                              void* d_out, int out_size, void* d_ws, size_t ws_size,
                              hipStream_t stream) {
    const float* x     = (const float*)d_in[0];
    const float* w_qkv = (const float*)d_in[1];
    const float* b_qkv = (const float*)d_in[2];
    const float* w_o   = (const float*)d_in[3];
    const float* b_o   = (const float*)d_in[4];
    float* out = (float*)d_out;

    const int M   = BATCH * SLEN;        // 4096
    const int XN  = M * DIN;             // 4,194,304
    const int WQN = E3 * DIN;            // 3,145,728
    const int WON = DMODEL * DMODEL;     // 1,048,576
    const size_t QKVN = (size_t)BATCH * SLEN * E3;

    us* qkvh = (us*)d_ws;                // fp16 qkv [QKVN]
    us* xh   = qkvh + QKVN;              // fp16 x [XN], reused for vals
    us* wq   = xh + XN;                  // fp16 w_qkv [WQN]
    us* wo   = wq + WQN;                 // fp16 w_o [WON]

    // 1) fp32 -> fp16 conversions, one launch
    cvt3_f16<<<dim3((XN + WQN + WON) / 2048), 256, 0, stream>>>(
        x, xh, XN, w_qkv, wq, WQN, w_o, wo);

    // 2) qkv = x @ w_qkv^T + b_qkv -> fp16 (Q cols pre-scaled by QSCALE)
    gemm_f16<true><<<dim3(E3 / 128, M / 128), 256, 0, stream>>>(
        xh, wq, b_qkv, qkvh, M, E3, DIN);

    // 3) attention -> vals fp16 (reuse x plane; x is dead)
    us* vals = xh;
    attn_mfma<<<dim3(SLEN / ABQ, BATCH * NHEAD), 512, 0, stream>>>(qkvh, vals);

    // 4) out = vals @ w_o^T + b_o -> fp32
    gemm_f16<false><<<dim3(DMODEL / 128, M / 128), 256, 0, stream>>>(
        vals, wo, b_o, out, M, DMODEL, DMODEL);
}

// Round 2
// 187.553 us; speedup vs baseline: 1.0718x; 1.0144x over previous
//
#include <hip/hip_runtime.h>
#include <hip/hip_bf16.h>
#include <math.h>

// Problem constants
#define BATCH 2
#define SLEN  2048
#define DIN   1024
#define DMODEL 1024
#define NHEAD 16
#define HD    64
#define E3    3072   // 3*DMODEL, row width of qkv

typedef unsigned short us;
typedef _Float16 f16;
typedef __attribute__((ext_vector_type(8))) _Float16 f16x8;
typedef __attribute__((ext_vector_type(8))) unsigned short us8;
typedef __attribute__((ext_vector_type(4))) unsigned short us4;
typedef __attribute__((ext_vector_type(4))) float f32x4;
typedef __attribute__((ext_vector_type(16))) float f32x16;
typedef __attribute__((ext_vector_type(4))) unsigned int u32x4;

// 0.125 (1/sqrt(HD)) * log2(e): folded into Q at qkv-GEMM epilogue so the
// attention softmax is a bare exp2 of the raw MFMA score.
#define QSCALE 0.18033688011112042f

__device__ __forceinline__ us f16bits(float x) {
    const f16 h = (f16)x;
    return __builtin_bit_cast(us, h);
}

__device__ __forceinline__ unsigned int pkrtz(float a, float b) {
    return __builtin_bit_cast(unsigned int, __builtin_amdgcn_cvt_pkrtz(a, b));
}

// v_permlane32_swap_b32: a' = {a.lo, b.lo}, b' = {a.hi, b.hi}
__device__ __forceinline__ void plswap(unsigned int& a, unsigned int& b) {
    asm volatile("v_permlane32_swap_b32 %0, %1" : "+v"(a), "+v"(b));
}

__device__ __forceinline__ void barrier_raw() {
    asm volatile("s_barrier" ::: "memory");
}

// async 16B global->LDS (lane i deposits at ldsbase + i*16)
#define GLL16(g, l)                                                                     \
    __builtin_amdgcn_global_load_lds((const __attribute__((address_space(1))) unsigned int*)(g), \
                                     (__attribute__((address_space(3))) unsigned int*)(l), 16, 0, 0)

// ---------------- fp32 -> fp16 for x, w_qkv, w_o in one launch ----------------
__global__ __launch_bounds__(256) void cvt3_f16(
    const float* __restrict__ x, us* __restrict__ ox, int nx,
    const float* __restrict__ wq, us* __restrict__ owq, int nq,
    const float* __restrict__ wo, us* __restrict__ owo)
{
    int i = (blockIdx.x * 256 + threadIdx.x) * 8;
    const float* s;
    us* o;
    if (i < nx)           { s = x;  o = ox; }
    else if (i < nx + nq) { s = wq; o = owq; i -= nx; }
    else                  { s = wo; o = owo; i -= nx + nq; }
    const float4 f0 = *(const float4*)&s[i];
    const float4 f1 = *(const float4*)&s[i + 4];
    const float v[8] = {f0.x, f0.y, f0.z, f0.w, f1.x, f1.y, f1.z, f1.w};
    us8 h;
#pragma unroll
    for (int j = 0; j < 8; ++j) h[j] = f16bits(v[j]);
    *(us8*)&o[i] = h;
}

// ---------------- 256x256 8-phase counted-vmcnt MFMA GEMM (qkv) ----------------
// C[M,N] = A[M,K]*B[N,K]^T + bias[N] -> fp16 out, Q cols pre-scaled by QSCALE.
// 512 thr = 8 waves, 1M x 8N decomposition: wave w owns C rows [0,256) x cols
// [w*32, w*32+32). BK=64, LDS = 2 dbuf x (A 32KB + B 32KB) = 128 KiB.
// Layout [256 rows][8 slots x 16B], slot XOR-swizzled by (row&7): reads are
// ~2-4-way max; global_load_lds keeps LINEAR dest + inverse-swizzled per-lane
// global source (both-sides-or-neither rule).
// Phases = M-quarters (wave-uniform consumption -> half-tiles free mid-tile):
//   A-half0 (rows 0..127)  read in ph1,ph2 -> freed after ph2
//   A-half1 (rows 128..255) read in ph3,ph4 -> freed at boundary
//   B-frags loaded ONCE per tile at ph1 -> B halves freed after ph1
// Staging schedule (tile t, buffers d=t&1, e=d^1), derived slot/wait-safe:
//   ph1: stage A-h1(t+1)->e, B-h0(t+1)->e   (slots freed end of tile t-1)
//   ph2: stage B-h1(t+1)->e                 (B(t-1) last read ph1(t-1))
//   ph3: stage A-h0(t+2)->d                 (A-h0(t) last read ph2(t))
//   ph4: vmcnt(2) [allow only A-h0(t+2) in flight] -> tile t+1 fully landed.
// Every staged half has >=3 phases of flight; counted vmcnt never drains to 0.
#define GBK 64
#define GNT (DIN / GBK)   // 16

template <bool QKV_OUT>
__global__ __launch_bounds__(512, 2) void gemm256_f16(
    const us* __restrict__ Am, const us* __restrict__ Bm,
    const float* __restrict__ bias, void* __restrict__ Cout,
    int M, int N, int K)
{
    __shared__ __align__(16) us lds[65536];   // 128 KiB
    us* const ldsA = lds;                     // [2][256][64]
    us* const ldsB = lds + 32768;

    const int t    = threadIdx.x;
    const int lane = t & 63;
    const int w    = t >> 6;        // wave 0..7
    const int ml   = lane & 15;
    const int quad = lane >> 4;
    const int msk  = ml & 7;

    // XCD-aware bijective block swizzle (nwg % 8 == 0)
    const int nbx = N >> 8;
    const int nwg = (M >> 8) * nbx;
    int wg = blockIdx.y * nbx + blockIdx.x;
    wg = (wg & 7) * (nwg >> 3) + (wg >> 3);
    const int m0 = (wg / nbx) * 256;
    const int n0 = (wg % nbx) * 256;

    // staging: wave w covers rows [w*16, w*16+16) of each 128-row half (2 glls)
    const int r8  = lane >> 3;                       // 0..7
    const int xsw = ((lane & 7) ^ r8) * 8;           // inverse-swizzled col (elems)
    const us* pA0 = Am + (size_t)(m0 + w * 16 + r8) * K + xsw;
    const us* pA1 = pA0 + (size_t)8 * K;
    const us* pB0 = Bm + (size_t)(n0 + w * 16 + r8) * K + xsw;
    const us* pB1 = pB0 + (size_t)8 * K;
    const int sdo = w * 1024;                        // us offset of wave chunk

#define STG_A(d, half, kk) do { \
    GLL16(pA0 + (size_t)(half) * 128 * K + (kk), &ldsA[(d) * 16384 + (half) * 8192 + sdo]); \
    GLL16(pA1 + (size_t)(half) * 128 * K + (kk), &ldsA[(d) * 16384 + (half) * 8192 + sdo + 512]); } while (0)
#define STG_B(d, half, kk) do { \
    GLL16(pB0 + (size_t)(half) * 128 * K + (kk), &ldsB[(d) * 16384 + (half) * 8192 + sdo]); \
    GLL16(pB1 + (size_t)(half) * 128 * K + (kk), &ldsB[(d) * 16384 + (half) * 8192 + sdo + 512]); } while (0)

    // swizzled fragment reads: row&7 == ml&7 at every frag site
#define LDA(d, mi, ks) __builtin_bit_cast(f16x8, *(const us8*)&ldsA[(d) * 16384 + ((mi) * 16 + ml) * 64 + (((quad ^ msk) ^ ((ks) << 2)) * 8)])
#define LDB(d, nj, ks) __builtin_bit_cast(f16x8, *(const us8*)&ldsB[(d) * 16384 + (w * 32 + (nj) * 16 + ml) * 64 + (((quad ^ msk) ^ ((ks) << 2)) * 8)])

    f32x4 acc[16][2];
#pragma unroll
    for (int i = 0; i < 16; ++i)
#pragma unroll
        for (int j = 0; j < 2; ++j) {
            acc[i][j][0] = 0.f; acc[i][j][1] = 0.f; acc[i][j][2] = 0.f; acc[i][j][3] = 0.f;
        }

#define PHASE(q) do { \
    f16x8 aa[4][2]; \
    _Pragma("unroll") for (int mi2 = 0; mi2 < 4; ++mi2) { \
        aa[mi2][0] = LDA(d, (q) * 4 + mi2, 0); \
        aa[mi2][1] = LDA(d, (q) * 4 + mi2, 1); } \
    __builtin_amdgcn_s_setprio(1); \
    _Pragma("unroll") for (int ks = 0; ks < 2; ++ks) \
    _Pragma("unroll") for (int nj = 0; nj < 2; ++nj) \
    _Pragma("unroll") for (int mi2 = 0; mi2 < 4; ++mi2) \
        acc[(q) * 4 + mi2][nj] = __builtin_amdgcn_mfma_f32_16x16x32_f16(aa[mi2][ks], bf[ks][nj], acc[(q) * 4 + mi2][nj], 0, 0, 0); \
    __builtin_amdgcn_s_setprio(0); \
} while (0)

    // ---- prologue: tile0 all halves + A-h0(1); tile0 landed, 1 half in flight ----
    STG_A(0, 0, 0); STG_A(0, 1, 0); STG_B(0, 0, 0); STG_B(0, 1, 0);
    STG_A(1, 0, GBK);
    asm volatile("s_waitcnt vmcnt(2)" ::: "memory");
    barrier_raw();

    for (int tt = 0; tt < GNT; ++tt) {
        const int d = tt & 1, e = d ^ 1;
        const int kn = (tt + 1) * GBK;

        // ---- phase 1: mi 0..3 ----
        if (tt + 1 < GNT) { STG_A(e, 1, kn); STG_B(e, 0, kn); }
        f16x8 bf[2][2];
#pragma unroll
        for (int ks = 0; ks < 2; ++ks)
#pragma unroll
            for (int nj = 0; nj < 2; ++nj)
                bf[ks][nj] = LDB(d, nj, ks);
        PHASE(0);
        barrier_raw();

        // ---- phase 2: mi 4..7 ----
        if (tt + 1 < GNT) STG_B(e, 1, kn);
        PHASE(1);
        barrier_raw();

        // ---- phase 3: mi 8..11 ----
        if (tt + 2 < GNT) STG_A(d, 0, kn + GBK);
        PHASE(2);
        barrier_raw();

        // ---- phase 4: mi 12..15 + counted boundary wait ----
        PHASE(3);
        if (tt + 2 < GNT)      { asm volatile("s_waitcnt vmcnt(2)" ::: "memory"); }
        else if (tt + 1 < GNT) { asm volatile("s_waitcnt vmcnt(0)" ::: "memory"); }
        barrier_raw();
    }

    // ---- epilogue: bias (+QSCALE on Q cols), fp16/fp32 store ----
    float bj[2], cs[2];
#pragma unroll
    for (int nj = 0; nj < 2; ++nj) {
        const int col = n0 + w * 32 + nj * 16 + ml;
        bj[nj] = bias[col];
        cs[nj] = (QKV_OUT && (col % 192) < 64) ? QSCALE : 1.0f;
    }
#pragma unroll
    for (int mi = 0; mi < 16; ++mi) {
#pragma unroll
        for (int r = 0; r < 4; ++r) {
            const size_t rowoff = (size_t)(m0 + mi * 16 + quad * 4 + r) * N;
#pragma unroll
            for (int nj = 0; nj < 2; ++nj) {
                const int col = n0 + w * 32 + nj * 16 + ml;
                const float v = (acc[mi][nj][r] + bj[nj]) * cs[nj];
                if (QKV_OUT) ((us*)Cout)[rowoff + col] = f16bits(v);
                else         ((float*)Cout)[rowoff + col] = v;
            }
        }
    }
#undef PHASE
#undef LDA
#undef LDB
#undef STG_A
#undef STG_B
}

// ---------------- 128x128 MFMA GEMM (kept for the out-projection: 256 blocks) --
template <bool QKV_OUT>
__global__ __launch_bounds__(256) void gemm_f16(
    const us* __restrict__ Am, const us* __restrict__ Bm,
    const float* __restrict__ bias, void* __restrict__ Cout,
    int M, int N, int K)
{
    __shared__ __align__(16) us As[128 * 32];
    __shared__ __align__(16) us Bs[128 * 32];

    const int t    = threadIdx.x;
    const int lane = t & 63;
    const int w    = t >> 6;
    const int ml   = lane & 15;
    const int quad = lane >> 4;
    const int wm   = w >> 1;
    const int wn   = w & 1;

    const int m0 = blockIdx.y * 128;
    const int n0 = blockIdx.x * 128;

    const int srow = (lane >> 2);
    const int scol = (lane & 3) * 8;

    const us* pA = Am + (size_t)(m0 + w * 32 + srow) * K + scol;
    const us* pB = Bm + (size_t)(n0 + w * 32 + srow) * K + scol;
    const size_t rstep = (size_t)16 * K;

    us* lA0 = &As[(w * 32) * 32];
    us* lA1 = &As[(w * 32 + 16) * 32];
    us* lB0 = &Bs[(w * 32) * 32];
    us* lB1 = &Bs[(w * 32 + 16) * 32];

    f32x4 acc[4][4];
#pragma unroll
    for (int i = 0; i < 4; ++i)
#pragma unroll
        for (int j = 0; j < 4; ++j) {
            acc[i][j][0] = 0.f; acc[i][j][1] = 0.f; acc[i][j][2] = 0.f; acc[i][j][3] = 0.f;
        }

    for (int k0 = 0; k0 < K; k0 += 32) {
        __syncthreads();
        GLL16(pA + k0, lA0); GLL16(pA + k0 + rstep, lA1);
        GLL16(pB + k0, lB0); GLL16(pB + k0 + rstep, lB1);
        __syncthreads();

        f16x8 a[4];
#pragma unroll
        for (int i = 0; i < 4; ++i)
            a[i] = __builtin_bit_cast(f16x8, *(const us8*)&As[(wm * 64 + i * 16 + ml) * 32 + quad * 8]);
#pragma unroll
        for (int j = 0; j < 4; ++j) {
            const f16x8 b = __builtin_bit_cast(f16x8, *(const us8*)&Bs[(wn * 64 + j * 16 + ml) * 32 + quad * 8]);
#pragma unroll
            for (int i = 0; i < 4; ++i)
                acc[i][j] = __builtin_amdgcn_mfma_f32_16x16x32_f16(a[i], b, acc[i][j], 0, 0, 0);
        }
    }

    float bj[4], cs[4];
#pragma unroll
    for (int j = 0; j < 4; ++j) {
        const int col = n0 + wn * 64 + j * 16 + ml;
        bj[j] = bias[col];
        cs[j] = (QKV_OUT && (col % 192) < 64) ? QSCALE : 1.0f;
    }

#pragma unroll
    for (int i = 0; i < 4; ++i) {
#pragma unroll
        for (int r = 0; r < 4; ++r) {
            const size_t rowoff = (size_t)(m0 + wm * 64 + i * 16 + quad * 4 + r) * N;
#pragma unroll
            for (int j = 0; j < 4; ++j) {
                const int col = n0 + wn * 64 + j * 16 + ml;
                const float v = (acc[i][j][r] + bj[j]) * cs[j];
                if (QKV_OUT) ((us*)Cout)[rowoff + col] = f16bits(v);
                else         ((float*)Cout)[rowoff + col] = v;
            }
        }
    }
}

// ---------------- MFMA flash attention, 32x32 shape, transposed-score ----------------
// (unchanged from R1: key-split 8 waves, T12 in-register P, exact split combine)
#define ABQ 128
#define ACH 64
#define NCH (SLEN / ACH)    // 32
#define NCH2 (NCH / 2)      // 16 chunks per split
#define LQA 72              // LDS row stride in fp16 elems
#define OSTR 68             // combine-scratch row stride in f32

__global__ __launch_bounds__(512, 4) void attn_mfma(
    const us* __restrict__ qkvh, us* __restrict__ vals)
{
    __shared__ __align__(16) us smem[27648];
    us* const Qs = smem;            // 9216 us
    us* const Ks = smem + 9216;     // 9216 us (2 x 4608)
    us* const Vt = smem + 18432;    // 9216 us (2 x 4608)

    const int t    = threadIdx.x;
    const int lane = t & 63;
    const int w    = t >> 6;        // wave 0..7
    const int sp   = w >> 2;        // key split 0/1
    const int wq4  = w & 3;         // q-group within split
    const int t2   = t & 255;       // thread id within split
    const int m32  = lane & 31;
    const int half = lane >> 5;

    const int bh = blockIdx.y;
    const int b  = bh >> 4;
    const int h  = bh & 15;
    const int q0 = blockIdx.x * ABQ;

    const size_t base = (size_t)b * SLEN * E3;
    const int qoff = h * 192;

    // ---- stage Q (128 q x 64 d): 16 elems / thread ----
    {
        const int row = t >> 2;
        const int c0q = (t & 3) * 16;
        const us* g = &qkvh[base + (size_t)(q0 + row) * E3 + qoff + c0q];
        *(us8*)&Qs[row * LQA + c0q]     = *(const us8*)g;
        *(us8*)&Qs[row * LQA + c0q + 8] = *(const us8*)(g + 8);
    }
    __syncthreads();

    f16x8 aq[4];
#pragma unroll
    for (int s = 0; s < 4; ++s)
        aq[s] = __builtin_bit_cast(f16x8, *(const us8*)&Qs[(wq4 * 32 + m32) * LQA + half * 8 + 16 * s]);

    const int krA = t2 >> 2;          // K: key 0..63, 16 dims/thread
    const int ksA = (t2 & 3) * 16;
    const int k2  = t2 & 31;          // V: key PAIR (2*k2, 2*k2+1)
    const int d0v = (t2 >> 5) * 8;    // V: 8 dims/thread

    us* const myK = Ks + sp * 4608;
    us* const myV = Vt + sp * 4608;
    const int cg0 = sp * NCH2;

    us8 kk0, kk1, vv0, vv1;
    {
        const us* gK = &qkvh[base + (size_t)(cg0 * ACH + krA) * E3 + qoff + 64 + ksA];
        kk0 = *(const us8*)gK; kk1 = *(const us8*)(gK + 8);
        const us* gV = &qkvh[base + (size_t)(cg0 * ACH + 2 * k2) * E3 + qoff + 128 + d0v];
        vv0 = *(const us8*)gV; vv1 = *(const us8*)(gV + E3);
    }

    f32x16 O[2];
#pragma unroll
    for (int dt = 0; dt < 2; ++dt)
#pragma unroll
        for (int r = 0; r < 16; ++r) O[dt][r] = 0.f;
    float lpart = 0.f;

    for (int c = 0; c < NCH2; ++c) {
        __syncthreads();
        *(us8*)&myK[krA * LQA + ksA]     = kk0;
        *(us8*)&myK[krA * LQA + ksA + 8] = kk1;
#pragma unroll
        for (int j = 0; j < 8; ++j) {
            const unsigned int pv = (unsigned int)vv0[j] | ((unsigned int)vv1[j] << 16);
            *(unsigned int*)&myV[(d0v + j) * LQA + 2 * k2] = pv;
        }
        __syncthreads();
        if (c + 1 < NCH2) {
            const int cg = cg0 + c + 1;
            const us* gK = &qkvh[base + (size_t)(cg * ACH + krA) * E3 + qoff + 64 + ksA];
            kk0 = *(const us8*)gK; kk1 = *(const us8*)(gK + 8);
            const us* gV = &qkvh[base + (size_t)(cg * ACH + 2 * k2) * E3 + qoff + 128 + d0v];
            vv0 = *(const us8*)gV; vv1 = *(const us8*)(gV + E3);
        }

        f16x8 pf[4];
#pragma unroll
        for (int kt = 0; kt < 2; ++kt) {
            f32x16 z;
#pragma unroll
            for (int r = 0; r < 16; ++r) z[r] = 0.f;
#pragma unroll
            for (int s = 0; s < 4; ++s) {
                const f16x8 ak = __builtin_bit_cast(f16x8, *(const us8*)&myK[(kt * 32 + m32) * LQA + half * 8 + 16 * s]);
                z = __builtin_amdgcn_mfma_f32_32x32x16_f16(ak, aq[s], z, 0, 0, 0);
            }
            float p[16];
#pragma unroll
            for (int r = 0; r < 16; ++r) {
                p[r] = __builtin_amdgcn_exp2f(z[r]);
                lpart += p[r];
            }
            unsigned int a0 = pkrtz(p[0],  p[1]),  a1 = pkrtz(p[2],  p[3]);
            unsigned int b0 = pkrtz(p[4],  p[5]),  b1 = pkrtz(p[6],  p[7]);
            plswap(a0, b0); plswap(a1, b1);
            pf[2 * kt] = __builtin_bit_cast(f16x8, (u32x4){a0, a1, b0, b1});
            unsigned int e0 = pkrtz(p[8],  p[9]),  e1 = pkrtz(p[10], p[11]);
            unsigned int f0 = pkrtz(p[12], p[13]), f1 = pkrtz(p[14], p[15]);
            plswap(e0, f0); plswap(e1, f1);
            pf[2 * kt + 1] = __builtin_bit_cast(f16x8, (u32x4){e0, e1, f0, f1});
        }

#pragma unroll
        for (int dt = 0; dt < 2; ++dt) {
#pragma unroll
            for (int s = 0; s < 4; ++s) {
                const f16x8 av = __builtin_bit_cast(f16x8, *(const us8*)&myV[(dt * 32 + m32) * LQA + half * 8 + 16 * s]);
                O[dt] = __builtin_amdgcn_mfma_f32_32x32x16_f16(av, pf[s], O[dt], 0, 0, 0);
            }
        }
    }

    const float l = lpart + __shfl_xor(lpart, 32);
    const int ql = wq4 * 32 + m32;

    __syncthreads();
    float* const Osc = (float*)(smem + 9216);
    float* const lsc = Osc + ABQ * OSTR;

    if (sp == 1) {
#pragma unroll
        for (int dt = 0; dt < 2; ++dt) {
#pragma unroll
            for (int g = 0; g < 4; ++g) {
                const f32x4 o4 = {O[dt][g * 4], O[dt][g * 4 + 1], O[dt][g * 4 + 2], O[dt][g * 4 + 3]};
                *(f32x4*)&Osc[ql * OSTR + dt * 32 + 8 * g + 4 * half] = o4;
            }
        }
        if (half == 0) lsc[ql] = l;
    }
    __syncthreads();
    if (sp == 0) {
        const float rl = 1.0f / (l + lsc[ql]);
        const int sq = q0 + ql;
        const size_t rowbase = (size_t)(b * SLEN + sq) * DMODEL + h * HD;
#pragma unroll
        for (int dt = 0; dt < 2; ++dt) {
#pragma unroll
            for (int g = 0; g < 4; ++g) {
                const f32x4 part = *(const f32x4*)&Osc[ql * OSTR + dt * 32 + 8 * g + 4 * half];
                us4 o4;
#pragma unroll
                for (int r2 = 0; r2 < 4; ++r2)
                    o4[r2] = f16bits((O[dt][g * 4 + r2] + part[r2]) * rl);
                *(us4*)&vals[rowbase + dt * 32 + 8 * g + 4 * half] = o4;
            }
        }
    }
}

// ---------------- launch ----------------
extern "C" void kernel_launch(void* const* d_in, const int* in_sizes, int n_in,
                              void* d_out, int out_size, void* d_ws, size_t ws_size,
                              hipStream_t stream) {
    const float* x     = (const float*)d_in[0];
    const float* w_qkv = (const float*)d_in[1];
    const float* b_qkv = (const float*)d_in[2];
    const float* w_o   = (const float*)d_in[3];
    const float* b_o   = (const float*)d_in[4];
    float* out = (float*)d_out;

    const int M   = BATCH * SLEN;        // 4096
    const int XN  = M * DIN;             // 4,194,304
    const int WQN = E3 * DIN;            // 3,145,728
    const int WON = DMODEL * DMODEL;     // 1,048,576
    const size_t QKVN = (size_t)BATCH * SLEN * E3;

    us* qkvh = (us*)d_ws;                // fp16 qkv [QKVN]
    us* xh   = qkvh + QKVN;              // fp16 x [XN], reused for vals
    us* wq   = xh + XN;                  // fp16 w_qkv [WQN]
    us* wo   = wq + WQN;                 // fp16 w_o [WON]

    // 1) fp32 -> fp16 conversions, one launch
    cvt3_f16<<<dim3((XN + WQN + WON) / 2048), 256, 0, stream>>>(
        x, xh, XN, w_qkv, wq, WQN, w_o, wo);

    // 2) qkv = x @ w_qkv^T + b_qkv -> fp16 (Q cols pre-scaled by QSCALE)
    //    256^2 8-phase counted-vmcnt kernel, 192 blocks
    gemm256_f16<true><<<dim3(E3 / 256, M / 256), 512, 0, stream>>>(
        xh, wq, b_qkv, qkvh, M, E3, DIN);

    // 3) attention -> vals fp16 (reuse x plane; x is dead)
    us* vals = xh;
    attn_mfma<<<dim3(SLEN / ABQ, BATCH * NHEAD), 512, 0, stream>>>(qkvh, vals);

    // 4) out = vals @ w_o^T + b_o -> fp32 (128^2 kernel: 256 blocks, full CU fill)
    gemm_f16<false><<<dim3(DMODEL / 128, M / 128), 256, 0, stream>>>(
        vals, wo, b_o, out, M, DMODEL, DMODEL);
}

// Round 3
// 185.526 us; speedup vs baseline: 1.0836x; 1.0109x over previous
//
#include <hip/hip_runtime.h>
#include <hip/hip_bf16.h>
#include <math.h>

// Problem constants
#define BATCH 2
#define SLEN  2048
#define DIN   1024
#define DMODEL 1024
#define NHEAD 16
#define HD    64
#define E3    3072   // 3*DMODEL, row width of qkv

typedef unsigned short us;
typedef _Float16 f16;
typedef __attribute__((ext_vector_type(8))) _Float16 f16x8;
typedef __attribute__((ext_vector_type(8))) unsigned short us8;
typedef __attribute__((ext_vector_type(4))) unsigned short us4;
typedef __attribute__((ext_vector_type(4))) float f32x4;
typedef __attribute__((ext_vector_type(16))) float f32x16;
typedef __attribute__((ext_vector_type(4))) unsigned int u32x4;

// 0.125 (1/sqrt(HD)) * log2(e): folded into Q at qkv-GEMM epilogue so the
// attention softmax is a bare exp2 of the raw MFMA score.
#define QSCALE 0.18033688011112042f

__device__ __forceinline__ us f16bits(float x) {
    const f16 h = (f16)x;
    return __builtin_bit_cast(us, h);
}

__device__ __forceinline__ unsigned int pkrtz(float a, float b) {
    return __builtin_bit_cast(unsigned int, __builtin_amdgcn_cvt_pkrtz(a, b));
}

// v_permlane32_swap_b32: a' = {a.lo, b.lo}, b' = {a.hi, b.hi}
__device__ __forceinline__ void plswap(unsigned int& a, unsigned int& b) {
    asm volatile("v_permlane32_swap_b32 %0, %1" : "+v"(a), "+v"(b));
}

__device__ __forceinline__ void barrier_raw() {
    asm volatile("s_barrier" ::: "memory");
}

// async 16B global->LDS (lane i deposits at ldsbase + i*16)
#define GLL16(g, l)                                                                     \
    __builtin_amdgcn_global_load_lds((const __attribute__((address_space(1))) unsigned int*)(g), \
                                     (__attribute__((address_space(3))) unsigned int*)(l), 16, 0, 0)

// ---------------- fp32 -> fp16 for x, w_qkv, w_o in one launch ----------------
__global__ __launch_bounds__(256) void cvt3_f16(
    const float* __restrict__ x, us* __restrict__ ox, int nx,
    const float* __restrict__ wq, us* __restrict__ owq, int nq,
    const float* __restrict__ wo, us* __restrict__ owo)
{
    int i = (blockIdx.x * 256 + threadIdx.x) * 8;
    const float* s;
    us* o;
    if (i < nx)           { s = x;  o = ox; }
    else if (i < nx + nq) { s = wq; o = owq; i -= nx; }
    else                  { s = wo; o = owo; i -= nx + nq; }
    const float4 f0 = *(const float4*)&s[i];
    const float4 f1 = *(const float4*)&s[i + 4];
    const float v[8] = {f0.x, f0.y, f0.z, f0.w, f1.x, f1.y, f1.z, f1.w};
    us8 h;
#pragma unroll
    for (int j = 0; j < 8; ++j) h[j] = f16bits(v[j]);
    *(us8*)&o[i] = h;
}

// ---------------- 128xBN double-buffered counted-vmcnt MFMA GEMM ----------------
// C[M,N] = A[M,K]*B[N,K]^T + bias[N]. 256 thr = 4 waves (2M x 2N); wave owns
// 64 x BN/2 of C. BK=64, LDS = 2buf x (A 128x64 + B BNx64) fp16 (64/48 KB ->
// 2-3 blocks/CU resident). Conflict-free b128 frag reads via slot^(row&7)
// swizzle: linear global_load_lds dest + inverse-swizzled per-lane GLOBAL
// source + XOR on read (both-sides rule, verified in R2's gemm256).
// Schedule per K-tile t (reads buffer d=t&1, e=d^1), counted vmcnt:
//   p0: issue STG_A(t+1)->e; read B-frags(all)+A-frags(mi0,1); MFMA; barrier
//   p1: issue STG_B(t+2)->d  [B(d) dead after p0]; A-frags(mi2,3); MFMA
//   boundary: vmcnt(BGL) -> A(t+1),B(t+1) landed, B(t+2) stays in flight.
// Steady state never drains vmcnt to 0 (T3/T4).
#define GBK 64
#define GNT (DIN / GBK)   // 16 (both GEMMs have K=1024)

template <int BN, bool QKV_OUT>
__global__ __launch_bounds__(256) void gemm_db(
    const us* __restrict__ Am, const us* __restrict__ Bm,
    const float* __restrict__ bias, void* __restrict__ Cout,
    int M, int N, int K)
{
    constexpr int NJ  = BN / 32;    // n-frags per wave (4 or 2)
    constexpr int BGL = BN / 32;    // B-staging GLLs per wave (4 or 2)
    __shared__ __align__(16) us ldsA[2 * 128 * 64];
    __shared__ __align__(16) us ldsB[2 * BN * 64];

    const int t    = threadIdx.x;
    const int lane = t & 63;
    const int w    = t >> 6;        // wave 0..3
    const int ml   = lane & 15;
    const int quad = lane >> 4;
    const int msk  = ml & 7;
    const int wm   = w >> 1;
    const int wn   = w & 1;

    // XCD-aware bijective block swizzle (nwg % 8 == 0 for both grids)
    const int nbx = N / BN;
    const int nwg = (M >> 7) * nbx;
    int wg = blockIdx.y * nbx + blockIdx.x;
    wg = (wg & 7) * (nwg >> 3) + (wg >> 3);
    const int m0 = (wg / nbx) * 128;
    const int n0 = (wg % nbx) * BN;

    // staging: lane covers (row8 = lane>>3, col-slot = lane&7); source slot
    // pre-XORed by row&7 so LINEAR LDS rows hold swizzled content.
    const int r8  = lane >> 3;
    const int xsw = ((lane & 7) ^ r8) * 8;
    const us* pA = Am + (size_t)(m0 + w * 32 + r8) * K + xsw;                  // 4 GLL x 8 rows
    const int brow = (BN == 128) ? w * 32 : w * 16;
    const us* pB = Bm + (size_t)(n0 + brow + r8) * K + xsw;                    // BGL GLL x 8 rows

#define STG_A(d, kk) do { _Pragma("unroll") for (int g = 0; g < 4; ++g) \
    GLL16(pA + (size_t)(8 * g) * K + (kk), &ldsA[(d) * 8192 + w * 2048 + g * 512]); } while (0)
#define STG_B(d, kk) do { _Pragma("unroll") for (int g = 0; g < BGL; ++g) \
    GLL16(pB + (size_t)(8 * g) * K + (kk), &ldsB[(d) * (BN * 64) + brow * 64 + g * 512]); } while (0)

    // swizzled fragment reads (row&7 == ml&7 at every frag row)
#define LDA(d, mi, ks) __builtin_bit_cast(f16x8, *(const us8*)&ldsA[(d) * 8192 + (wm * 64 + (mi) * 16 + ml) * 64 + (((quad ^ msk) ^ ((ks) << 2)) * 8)])
#define LDB(d, nj, ks) __builtin_bit_cast(f16x8, *(const us8*)&ldsB[(d) * (BN * 64) + (wn * (BN / 2) + (nj) * 16 + ml) * 64 + (((quad ^ msk) ^ ((ks) << 2)) * 8)])

#define WAIT_BGL() do { if constexpr (BN == 128) asm volatile("s_waitcnt vmcnt(4)" ::: "memory"); \
                        else                     asm volatile("s_waitcnt vmcnt(2)" ::: "memory"); } while (0)

    f32x4 acc[4][NJ];
#pragma unroll
    for (int i = 0; i < 4; ++i)
#pragma unroll
        for (int j = 0; j < NJ; ++j) {
            acc[i][j][0] = 0.f; acc[i][j][1] = 0.f; acc[i][j][2] = 0.f; acc[i][j][3] = 0.f;
        }

    // ---- prologue: tile0 full -> b0; B(1) -> b1 stays in flight ----
    STG_A(0, 0); STG_B(0, 0);
    STG_B(1, GBK);
    WAIT_BGL();
    barrier_raw();

    for (int tt = 0; tt < GNT; ++tt) {
        const int d = tt & 1, e = d ^ 1;

        // ---- p0: stage A(t+1); compute mi 0..1 with all B-frags ----
        if (tt + 1 < GNT) STG_A(e, (tt + 1) * GBK);
        f16x8 bf[2][NJ];
#pragma unroll
        for (int ks = 0; ks < 2; ++ks)
#pragma unroll
            for (int nj = 0; nj < NJ; ++nj)
                bf[ks][nj] = LDB(d, nj, ks);
        f16x8 a0[2][2];
#pragma unroll
        for (int mi = 0; mi < 2; ++mi) {
            a0[mi][0] = LDA(d, mi, 0);
            a0[mi][1] = LDA(d, mi, 1);
        }
        __builtin_amdgcn_s_setprio(1);
#pragma unroll
        for (int ks = 0; ks < 2; ++ks)
#pragma unroll
            for (int nj = 0; nj < NJ; ++nj)
#pragma unroll
                for (int mi = 0; mi < 2; ++mi)
                    acc[mi][nj] = __builtin_amdgcn_mfma_f32_16x16x32_f16(a0[mi][ks], bf[ks][nj], acc[mi][nj], 0, 0, 0);
        __builtin_amdgcn_s_setprio(0);
        barrier_raw();

        // ---- p1: stage B(t+2) into d (B(d) dead); compute mi 2..3 ----
        if (tt + 2 < GNT) STG_B(d, (tt + 2) * GBK);
        f16x8 a1[2][2];
#pragma unroll
        for (int mi = 0; mi < 2; ++mi) {
            a1[mi][0] = LDA(d, mi + 2, 0);
            a1[mi][1] = LDA(d, mi + 2, 1);
        }
        __builtin_amdgcn_s_setprio(1);
#pragma unroll
        for (int ks = 0; ks < 2; ++ks)
#pragma unroll
            for (int nj = 0; nj < NJ; ++nj)
#pragma unroll
                for (int mi = 0; mi < 2; ++mi)
                    acc[mi + 2][nj] = __builtin_amdgcn_mfma_f32_16x16x32_f16(a1[mi][ks], bf[ks][nj], acc[mi + 2][nj], 0, 0, 0);
        __builtin_amdgcn_s_setprio(0);

        // ---- boundary: counted wait (t+1 landed; B(t+2) stays in flight) ----
        if (tt + 2 < GNT)      WAIT_BGL();
        else if (tt + 1 < GNT) asm volatile("s_waitcnt vmcnt(0)" ::: "memory");
        barrier_raw();
    }

    // ---- epilogue: bias (+QSCALE on Q cols), fp16/fp32 store ----
    float bj[NJ], cs[NJ];
#pragma unroll
    for (int nj = 0; nj < NJ; ++nj) {
        const int col = n0 + wn * (BN / 2) + nj * 16 + ml;
        bj[nj] = bias[col];
        cs[nj] = (QKV_OUT && (col % 192) < 64) ? QSCALE : 1.0f;
    }
#pragma unroll
    for (int mi = 0; mi < 4; ++mi) {
#pragma unroll
        for (int r = 0; r < 4; ++r) {
            const size_t rowoff = (size_t)(m0 + wm * 64 + mi * 16 + quad * 4 + r) * N;
#pragma unroll
            for (int nj = 0; nj < NJ; ++nj) {
                const int col = n0 + wn * (BN / 2) + nj * 16 + ml;
                const float v = (acc[mi][nj][r] + bj[nj]) * cs[nj];
                if (QKV_OUT) ((us*)Cout)[rowoff + col] = f16bits(v);
                else         ((float*)Cout)[rowoff + col] = v;
            }
        }
    }
#undef STG_A
#undef STG_B
#undef LDA
#undef LDB
#undef WAIT_BGL
}

// ---------------- MFMA flash attention, 32x32 shape, transposed-score ----------------
// R1 structure (8-wave key-split, T12 in-register P, exact split combine) +
// T1 XCD swizzle: 1D grid 512; same-bh q-blocks land on ONE XCD so K/V
// (0.5 MB per bh, 4 bh per XCD = 2 MB) stays L2-resident instead of being
// refetched by ~5 XCDs (R2 FETCH: 69.7 MB vs 12.6 MB of qkv data).
#define ABQ 128
#define ACH 64
#define NCH (SLEN / ACH)    // 32
#define NCH2 (NCH / 2)      // 16 chunks per split
#define LQA 72              // LDS row stride in fp16 elems
#define OSTR 68             // combine-scratch row stride in f32

__global__ __launch_bounds__(512, 4) void attn_mfma(
    const us* __restrict__ qkvh, us* __restrict__ vals)
{
    __shared__ __align__(16) us smem[27648];
    us* const Qs = smem;            // 9216 us
    us* const Ks = smem + 9216;     // 9216 us (2 x 4608)
    us* const Vt = smem + 18432;    // 9216 us (2 x 4608)

    const int t    = threadIdx.x;
    const int lane = t & 63;
    const int w    = t >> 6;        // wave 0..7
    const int sp   = w >> 2;        // key split 0/1
    const int wq4  = w & 3;         // q-group within split
    const int t2   = t & 255;       // thread id within split
    const int m32  = lane & 31;
    const int half = lane >> 5;

    // XCD-owning decomposition: xcd = wg&7; bh = ((wg>>7)<<3)|xcd; qi = (wg>>3)&15
    const int wg  = blockIdx.x;
    const int s9  = wg >> 3;
    const int bh  = ((s9 >> 4) << 3) | (wg & 7);
    const int b   = bh >> 4;
    const int h   = bh & 15;
    const int q0  = (s9 & 15) * ABQ;

    const size_t base = (size_t)b * SLEN * E3;
    const int qoff = h * 192;

    // ---- stage Q (128 q x 64 d): 16 elems / thread ----
    {
        const int row = t >> 2;
        const int c0q = (t & 3) * 16;
        const us* g = &qkvh[base + (size_t)(q0 + row) * E3 + qoff + c0q];
        *(us8*)&Qs[row * LQA + c0q]     = *(const us8*)g;
        *(us8*)&Qs[row * LQA + c0q + 8] = *(const us8*)(g + 8);
    }
    __syncthreads();

    f16x8 aq[4];
#pragma unroll
    for (int s = 0; s < 4; ++s)
        aq[s] = __builtin_bit_cast(f16x8, *(const us8*)&Qs[(wq4 * 32 + m32) * LQA + half * 8 + 16 * s]);

    const int krA = t2 >> 2;          // K: key 0..63, 16 dims/thread
    const int ksA = (t2 & 3) * 16;
    const int k2  = t2 & 31;          // V: key PAIR (2*k2, 2*k2+1)
    const int d0v = (t2 >> 5) * 8;    // V: 8 dims/thread

    us* const myK = Ks + sp * 4608;
    us* const myV = Vt + sp * 4608;
    const int cg0 = sp * NCH2;

    us8 kk0, kk1, vv0, vv1;
    {
        const us* gK = &qkvh[base + (size_t)(cg0 * ACH + krA) * E3 + qoff + 64 + ksA];
        kk0 = *(const us8*)gK; kk1 = *(const us8*)(gK + 8);
        const us* gV = &qkvh[base + (size_t)(cg0 * ACH + 2 * k2) * E3 + qoff + 128 + d0v];
        vv0 = *(const us8*)gV; vv1 = *(const us8*)(gV + E3);
    }

    f32x16 O[2];
#pragma unroll
    for (int dt = 0; dt < 2; ++dt)
#pragma unroll
        for (int r = 0; r < 16; ++r) O[dt][r] = 0.f;
    float lpart = 0.f;

    for (int c = 0; c < NCH2; ++c) {
        __syncthreads();
        *(us8*)&myK[krA * LQA + ksA]     = kk0;
        *(us8*)&myK[krA * LQA + ksA + 8] = kk1;
#pragma unroll
        for (int j = 0; j < 8; ++j) {
            const unsigned int pv = (unsigned int)vv0[j] | ((unsigned int)vv1[j] << 16);
            *(unsigned int*)&myV[(d0v + j) * LQA + 2 * k2] = pv;
        }
        __syncthreads();
        if (c + 1 < NCH2) {
            const int cg = cg0 + c + 1;
            const us* gK = &qkvh[base + (size_t)(cg * ACH + krA) * E3 + qoff + 64 + ksA];
            kk0 = *(const us8*)gK; kk1 = *(const us8*)(gK + 8);
            const us* gV = &qkvh[base + (size_t)(cg * ACH + 2 * k2) * E3 + qoff + 128 + d0v];
            vv0 = *(const us8*)gV; vv1 = *(const us8*)(gV + E3);
        }

        f16x8 pf[4];
#pragma unroll
        for (int kt = 0; kt < 2; ++kt) {
            f32x16 z;
#pragma unroll
            for (int r = 0; r < 16; ++r) z[r] = 0.f;
#pragma unroll
            for (int s = 0; s < 4; ++s) {
                const f16x8 ak = __builtin_bit_cast(f16x8, *(const us8*)&myK[(kt * 32 + m32) * LQA + half * 8 + 16 * s]);
                z = __builtin_amdgcn_mfma_f32_32x32x16_f16(ak, aq[s], z, 0, 0, 0);
            }
            float p[16];
#pragma unroll
            for (int r = 0; r < 16; ++r) {
                p[r] = __builtin_amdgcn_exp2f(z[r]);
                lpart += p[r];
            }
            unsigned int a0 = pkrtz(p[0],  p[1]),  a1 = pkrtz(p[2],  p[3]);
            unsigned int b0 = pkrtz(p[4],  p[5]),  b1 = pkrtz(p[6],  p[7]);
            plswap(a0, b0); plswap(a1, b1);
            pf[2 * kt] = __builtin_bit_cast(f16x8, (u32x4){a0, a1, b0, b1});
            unsigned int e0 = pkrtz(p[8],  p[9]),  e1 = pkrtz(p[10], p[11]);
            unsigned int f0 = pkrtz(p[12], p[13]), f1 = pkrtz(p[14], p[15]);
            plswap(e0, f0); plswap(e1, f1);
            pf[2 * kt + 1] = __builtin_bit_cast(f16x8, (u32x4){e0, e1, f0, f1});
        }

#pragma unroll
        for (int dt = 0; dt < 2; ++dt) {
#pragma unroll
            for (int s = 0; s < 4; ++s) {
                const f16x8 av = __builtin_bit_cast(f16x8, *(const us8*)&myV[(dt * 32 + m32) * LQA + half * 8 + 16 * s]);
                O[dt] = __builtin_amdgcn_mfma_f32_32x32x16_f16(av, pf[s], O[dt], 0, 0, 0);
            }
        }
    }

    const float l = lpart + __shfl_xor(lpart, 32);
    const int ql = wq4 * 32 + m32;

    __syncthreads();
    float* const Osc = (float*)(smem + 9216);
    float* const lsc = Osc + ABQ * OSTR;

    if (sp == 1) {
#pragma unroll
        for (int dt = 0; dt < 2; ++dt) {
#pragma unroll
            for (int g = 0; g < 4; ++g) {
                const f32x4 o4 = {O[dt][g * 4], O[dt][g * 4 + 1], O[dt][g * 4 + 2], O[dt][g * 4 + 3]};
                *(f32x4*)&Osc[ql * OSTR + dt * 32 + 8 * g + 4 * half] = o4;
            }
        }
        if (half == 0) lsc[ql] = l;
    }
    __syncthreads();
    if (sp == 0) {
        const float rl = 1.0f / (l + lsc[ql]);
        const int sq = q0 + ql;
        const size_t rowbase = (size_t)(b * SLEN + sq) * DMODEL + h * HD;
#pragma unroll
        for (int dt = 0; dt < 2; ++dt) {
#pragma unroll
            for (int g = 0; g < 4; ++g) {
                const f32x4 part = *(const f32x4*)&Osc[ql * OSTR + dt * 32 + 8 * g + 4 * half];
                us4 o4;
#pragma unroll
                for (int r2 = 0; r2 < 4; ++r2)
                    o4[r2] = f16bits((O[dt][g * 4 + r2] + part[r2]) * rl);
                *(us4*)&vals[rowbase + dt * 32 + 8 * g + 4 * half] = o4;
            }
        }
    }
}

// ---------------- launch ----------------
extern "C" void kernel_launch(void* const* d_in, const int* in_sizes, int n_in,
                              void* d_out, int out_size, void* d_ws, size_t ws_size,
                              hipStream_t stream) {
    const float* x     = (const float*)d_in[0];
    const float* w_qkv = (const float*)d_in[1];
    const float* b_qkv = (const float*)d_in[2];
    const float* w_o   = (const float*)d_in[3];
    const float* b_o   = (const float*)d_in[4];
    float* out = (float*)d_out;

    const int M   = BATCH * SLEN;        // 4096
    const int XN  = M * DIN;             // 4,194,304
    const int WQN = E3 * DIN;            // 3,145,728
    const int WON = DMODEL * DMODEL;     // 1,048,576
    const size_t QKVN = (size_t)BATCH * SLEN * E3;

    us* qkvh = (us*)d_ws;                // fp16 qkv [QKVN]
    us* xh   = qkvh + QKVN;              // fp16 x [XN], reused for vals
    us* wq   = xh + XN;                  // fp16 w_qkv [WQN]
    us* wo   = wq + WQN;                 // fp16 w_o [WON]

    // 1) fp32 -> fp16 conversions, one launch
    cvt3_f16<<<dim3((XN + WQN + WON) / 2048), 256, 0, stream>>>(
        x, xh, XN, w_qkv, wq, WQN, w_o, wo);

    // 2) qkv = x @ w_qkv^T + b_qkv -> fp16 (Q cols pre-scaled by QSCALE)
    //    128x128 dbuf counted-vmcnt kernel: 768 blocks, 2 resident/CU
    gemm_db<128, true><<<dim3(E3 / 128, M / 128), 256, 0, stream>>>(
        xh, wq, b_qkv, qkvh, M, E3, DIN);

    // 3) attention -> vals fp16 (reuse x plane; x is dead); 1D grid, XCD-owned bh
    us* vals = xh;
    attn_mfma<<<dim3((SLEN / ABQ) * BATCH * NHEAD), 512, 0, stream>>>(qkvh, vals);

    // 4) out = vals @ w_o^T + b_o -> fp32; 128x64 tiles: 512 blocks, 2/CU
    gemm_db<64, false><<<dim3(DMODEL / 64, M / 128), 256, 0, stream>>>(
        vals, wo, b_o, out, M, DMODEL, DMODEL);
}